// Round 3
// baseline (485.564 us; speedup 1.0000x reference)
//
#include <hip/hip_runtime.h>
#include <hip/hip_bf16.h>

#define NB 4096
#define DK 1024           // elements per row (fp8 row = 1024 B)
#define EPSF 1e-6f
#define QSCALE 16.0f      // fp8 pre-scale (power of 2; cancelled exactly in exp)

typedef __attribute__((ext_vector_type(8))) int   i32x8_t;
typedef __attribute__((ext_vector_type(4))) int   i32x4_t;
typedef __attribute__((ext_vector_type(4))) float f32x4_t;

// async global->LDS, 16 B per lane. LDS dest is wave-uniform base + lane*16.
__device__ __forceinline__ void async16(const void* g, void* lds) {
    __builtin_amdgcn_global_load_lds(
        (const __attribute__((address_space(1))) void*)g,
        (__attribute__((address_space(3))) void*)lds, 16, 0, 0);
}

// ---------------------------------------------------------------------------
// Kernel 1: wave-per-row normalize of x and y -> fp8 e4m3 (x QSCALE), plus
// exact fp32 diagonal cos-sim. Also zeroes rowsum/colsum and the ticket.
// 4 rows per 256-thread block, no __syncthreads.
// ---------------------------------------------------------------------------
__global__ __launch_bounds__(256) void normalize_rows(
    const float* __restrict__ x, const float* __restrict__ y,
    unsigned* __restrict__ xq, unsigned* __restrict__ yq,   // fp8 rows: 256 uints
    float* __restrict__ sdiag, float* __restrict__ zerobuf,
    unsigned* __restrict__ ticket)
{
    const int t = threadIdx.x;
    const int gid = blockIdx.x * 256 + t;
    if (gid < 2 * NB) zerobuf[gid] = 0.f;   // rowsum+colsum contiguous
    if (gid == 0) *ticket = 0u;

    const int wave = t >> 6;
    const int lane = t & 63;
    const int row  = blockIdx.x * 4 + wave;

    const float4* xr = reinterpret_cast<const float4*>(x + (size_t)row * DK);
    const float4* yr = reinterpret_cast<const float4*>(y + (size_t)row * DK);

    float4 xv[4], yv[4];
    float ssx = 0.f, ssy = 0.f, sxy = 0.f;
    #pragma unroll
    for (int j = 0; j < 4; ++j) {
        xv[j] = xr[j * 64 + lane];
        yv[j] = yr[j * 64 + lane];
        ssx += xv[j].x*xv[j].x + xv[j].y*xv[j].y + xv[j].z*xv[j].z + xv[j].w*xv[j].w;
        ssy += yv[j].x*yv[j].x + yv[j].y*yv[j].y + yv[j].z*yv[j].z + yv[j].w*yv[j].w;
        sxy += xv[j].x*yv[j].x + xv[j].y*yv[j].y + xv[j].z*yv[j].z + xv[j].w*yv[j].w;
    }
    #pragma unroll
    for (int off = 1; off < 64; off <<= 1) {
        ssx += __shfl_xor(ssx, off, 64);
        ssy += __shfl_xor(ssy, off, 64);
        sxy += __shfl_xor(sxy, off, 64);
    }
    const float invx = 1.0f / fmaxf(sqrtf(ssx), EPSF);
    const float invy = 1.0f / fmaxf(sqrtf(ssy), EPSF);
    const float sx = invx * QSCALE;
    const float sy = invy * QSCALE;

    unsigned* xw = xq + (size_t)row * 256;
    unsigned* yw = yq + (size_t)row * 256;
    #pragma unroll
    for (int j = 0; j < 4; ++j) {
        int px = __builtin_amdgcn_cvt_pk_fp8_f32(xv[j].x * sx, xv[j].y * sx, 0, false);
        px     = __builtin_amdgcn_cvt_pk_fp8_f32(xv[j].z * sx, xv[j].w * sx, px, true);
        int py = __builtin_amdgcn_cvt_pk_fp8_f32(yv[j].x * sy, yv[j].y * sy, 0, false);
        py     = __builtin_amdgcn_cvt_pk_fp8_f32(yv[j].z * sy, yv[j].w * sy, py, true);
        xw[j * 64 + lane] = (unsigned)px;
        yw[j * 64 + lane] = (unsigned)py;
    }
    if (lane == 0) sdiag[row] = sxy * invx * invy;
}

// load one A/B fragment for mfma_scale_f32_16x16x128_f8f6f4:
// row base + 32 B of k (two 16 B groups 2q, 2q+1, XOR-swizzled by row&7).
__device__ __forceinline__ i32x8_t ld_frag(const unsigned char* base, int q, int h) {
    const i32x4_t lo = *reinterpret_cast<const i32x4_t*>(base + (((2*q)     ^ h) << 4));
    const i32x4_t hi = *reinterpret_cast<const i32x4_t*>(base + (((2*q + 1) ^ h) << 4));
    i32x8_t r;
    r[0] = lo[0]; r[1] = lo[1]; r[2] = lo[2]; r[3] = lo[3];
    r[4] = hi[0]; r[5] = hi[1]; r[6] = hi[2]; r[7] = hi[3];
    return r;
}

// ---------------------------------------------------------------------------
// Kernel 2: S' = 256 * xn*yn^T via MX-fp8 (unit scales), 128x128 tiles,
// BK=128 -> 8 K-iterations, 16 mfma_scale_f32_16x16x128 per wave per iter.
// LDS: 128 B rows, 8 x 16B groups, slot = g ^ (row&7) (round-2 scheme,
// measured 0 bank conflicts). Epilogue: E = exp2(S' / (256*TAU*ln2)),
// shuffle-reduced row/col partials, one atomicAdd per row/col per wave.
// Last block (device-scope ticket) computes the final loss.
// ---------------------------------------------------------------------------
__global__ __launch_bounds__(256, 4) void gemm_exp_sums(
    const unsigned char* __restrict__ xq, const unsigned char* __restrict__ yq,
    float* __restrict__ rowsum, float* __restrict__ colsum,
    const float* __restrict__ sdiag, float* __restrict__ out,
    unsigned* __restrict__ ticket)
{
    __shared__ __align__(16) unsigned char At[128 * 128];  // 16 KB
    __shared__ __align__(16) unsigned char Bt[128 * 128];  // 16 KB

    const int t    = threadIdx.x;
    const int lane = t & 63;
    const int wave = t >> 6;
    const int q    = lane >> 4;    // quad within wave
    const int l15  = lane & 15;
    const int h    = l15 & 7;      // row&7 for this lane's fragment rows

    const int R0 = blockIdx.y * 128;
    const int C0 = blockIdx.x * 128;
    const int wRow = (wave >> 1) * 64;   // wave's 64x64 quadrant
    const int wCol = (wave & 1) * 64;

    f32x4_t acc[4][4];
    #pragma unroll
    for (int i = 0; i < 4; i++)
        #pragma unroll
        for (int j = 0; j < 4; j++)
            acc[i][j] = (f32x4_t){0.f, 0.f, 0.f, 0.f};

    const int r8  = lane >> 3;           // row within 8-row staging chunk
    const int gsw = (lane & 7) ^ r8;     // swizzled source 16B-group

    for (int kb = 0; kb < DK; kb += 128) {
        __syncthreads();
        #pragma unroll
        for (int c = 0; c < 4; ++c) {
            const int rl = wave * 32 + c * 8 + r8;          // local row 0..127
            async16(xq + (size_t)(R0 + rl) * DK + kb + gsw * 16,
                    &At[(wave * 32 + c * 8) * 128]);
            async16(yq + (size_t)(C0 + rl) * DK + kb + gsw * 16,
                    &Bt[(wave * 32 + c * 8) * 128]);
        }
        __syncthreads();

        i32x8_t bfr[4];
        #pragma unroll
        for (int nt = 0; nt < 4; ++nt)
            bfr[nt] = ld_frag(&Bt[(wCol + nt * 16 + l15) * 128], q, h);

        #pragma unroll
        for (int mt = 0; mt < 4; ++mt) {
            const i32x8_t af = ld_frag(&At[(wRow + mt * 16 + l15) * 128], q, h);
            #pragma unroll
            for (int nt = 0; nt < 4; ++nt)
                acc[mt][nt] = __builtin_amdgcn_mfma_scale_f32_16x16x128_f8f6f4(
                    af, bfr[nt], acc[mt][nt],
                    0, 0,                       // cbsz=fp8(e4m3), blgp=fp8(e4m3)
                    0, 0x7F7F7F7F,              // A scales: E8M0 127 = 2^0
                    0, 0x7F7F7F7F);             // B scales: 2^0
        }
    }

    // Epilogue: E = exp(S/TAU); acc holds 256*S -> exp2(acc / (256*TAU*ln2)).
    const float kScale = (float)(1.0 / (256.0 * 0.07 * 0.6931471805599453));
    float csum[4] = {0.f, 0.f, 0.f, 0.f};
    #pragma unroll
    for (int mt = 0; mt < 4; ++mt) {
        float rsum[4] = {0.f, 0.f, 0.f, 0.f};
        #pragma unroll
        for (int nt = 0; nt < 4; ++nt) {
            #pragma unroll
            for (int r = 0; r < 4; ++r) {
                const float e = exp2f(acc[mt][nt][r] * kScale);
                rsum[r]  += e;
                csum[nt] += e;
            }
        }
        #pragma unroll
        for (int r = 0; r < 4; ++r) {
            float v = rsum[r];
            v += __shfl_xor(v, 1, 64);
            v += __shfl_xor(v, 2, 64);
            v += __shfl_xor(v, 4, 64);
            v += __shfl_xor(v, 8, 64);
            if (l15 == 0)
                atomicAdd(&rowsum[R0 + wRow + mt * 16 + q * 4 + r], v);
        }
    }
    #pragma unroll
    for (int nt = 0; nt < 4; ++nt) {
        float v = csum[nt];
        v += __shfl_xor(v, 16, 64);
        v += __shfl_xor(v, 32, 64);
        if (lane < 16)
            atomicAdd(&colsum[C0 + wCol + nt * 16 + l15], v);
    }

    // ---- fused finalize: last block to finish computes the loss ----------
    __threadfence();                       // release our atomics (agent scope)
    __shared__ unsigned rank;
    if (t == 0) rank = atomicAdd(ticket, 1u);
    __syncthreads();
    if (rank == (unsigned)(gridDim.x * gridDim.y - 1)) {
        __threadfence();                   // acquire: see all blocks' sums
        const float extra = (float)(NB * 1e-6 + 1e-6);
        double local = 0.0;
        for (int i = t; i < NB; i += 256) {
            local += (double)sdiag[i] * (2.0 / 0.07)
                   - (double)logf(rowsum[i] + extra)
                   - (double)logf(colsum[i] + extra);
        }
        #pragma unroll
        for (int off = 1; off < 64; off <<= 1)
            local += __shfl_xor(local, off, 64);
        __shared__ double dred[4];
        if ((t & 63) == 0) dred[t >> 6] = local;
        __syncthreads();
        if (t == 0) {
            const double tot = dred[0] + dred[1] + dred[2] + dred[3];
            out[0] = (float)(tot * (-1.0 / (2.0 * NB)));
        }
    }
}

// ---------------------------------------------------------------------------
extern "C" void kernel_launch(void* const* d_in, const int* in_sizes, int n_in,
                              void* d_out, int out_size, void* d_ws, size_t ws_size,
                              hipStream_t stream)
{
    const float* x = (const float*)d_in[0];
    const float* y = (const float*)d_in[1];
    float* out = (float*)d_out;

    char* ws = (char*)d_ws;
    unsigned char* xq = (unsigned char*)ws;                                 // 4 MB
    unsigned char* yq = (unsigned char*)(ws + (size_t)4 * 1024 * 1024);     // 4 MB
    float* rowsum = (float*)(ws + (size_t)8 * 1024 * 1024);                 // 16 KB
    float* colsum = rowsum + NB;                                            // 16 KB
    float* sdiag  = colsum + NB;                                            // 16 KB
    unsigned* ticket = (unsigned*)(sdiag + NB);                             // 4 B

    normalize_rows<<<NB / 4, 256, 0, stream>>>(x, y, (unsigned*)xq, (unsigned*)yq,
                                               sdiag, rowsum, ticket);

    dim3 grid(NB / 128, NB / 128);
    gemm_exp_sums<<<grid, 256, 0, stream>>>(xq, yq, rowsum, colsum, sdiag, out, ticket);
}

// Round 4
// 185.332 us; speedup vs baseline: 2.6200x; 2.6200x over previous
//
#include <hip/hip_runtime.h>
#include <hip/hip_bf16.h>

#define NB 4096
#define DK 1024           // elements per row (fp8 row = 1024 B)
#define EPSF 1e-6f
#define QSCALE 16.0f      // fp8 pre-scale (power of 2; cancelled exactly in exp)

typedef __attribute__((ext_vector_type(8))) int   i32x8_t;
typedef __attribute__((ext_vector_type(4))) int   i32x4_t;
typedef __attribute__((ext_vector_type(4))) float f32x4_t;

// async global->LDS, 16 B per lane. LDS dest is wave-uniform base + lane*16.
__device__ __forceinline__ void async16(const void* g, void* lds) {
    __builtin_amdgcn_global_load_lds(
        (const __attribute__((address_space(1))) void*)g,
        (__attribute__((address_space(3))) void*)lds, 16, 0, 0);
}

// ---------------------------------------------------------------------------
// Kernel 1: wave-per-row normalize of x and y -> fp8 e4m3 (x QSCALE), plus
// exact fp32 diagonal cos-sim. Also zeroes rowsum/colsum and the ticket.
// 4 rows per 256-thread block, no __syncthreads.
// ---------------------------------------------------------------------------
__global__ __launch_bounds__(256) void normalize_rows(
    const float* __restrict__ x, const float* __restrict__ y,
    unsigned* __restrict__ xq, unsigned* __restrict__ yq,   // fp8 rows: 256 uints
    float* __restrict__ sdiag, float* __restrict__ zerobuf,
    unsigned* __restrict__ ticket)
{
    const int t = threadIdx.x;
    const int gid = blockIdx.x * 256 + t;
    if (gid < 2 * NB) zerobuf[gid] = 0.f;   // rowsum+colsum contiguous
    if (gid == 0) *ticket = 0u;

    const int wave = t >> 6;
    const int lane = t & 63;
    const int row  = blockIdx.x * 4 + wave;

    const float4* xr = reinterpret_cast<const float4*>(x + (size_t)row * DK);
    const float4* yr = reinterpret_cast<const float4*>(y + (size_t)row * DK);

    float4 xv[4], yv[4];
    float ssx = 0.f, ssy = 0.f, sxy = 0.f;
    #pragma unroll
    for (int j = 0; j < 4; ++j) {
        xv[j] = xr[j * 64 + lane];
        yv[j] = yr[j * 64 + lane];
        ssx += xv[j].x*xv[j].x + xv[j].y*xv[j].y + xv[j].z*xv[j].z + xv[j].w*xv[j].w;
        ssy += yv[j].x*yv[j].x + yv[j].y*yv[j].y + yv[j].z*yv[j].z + yv[j].w*yv[j].w;
        sxy += xv[j].x*yv[j].x + xv[j].y*yv[j].y + xv[j].z*yv[j].z + xv[j].w*yv[j].w;
    }
    #pragma unroll
    for (int off = 1; off < 64; off <<= 1) {
        ssx += __shfl_xor(ssx, off, 64);
        ssy += __shfl_xor(ssy, off, 64);
        sxy += __shfl_xor(sxy, off, 64);
    }
    const float invx = 1.0f / fmaxf(sqrtf(ssx), EPSF);
    const float invy = 1.0f / fmaxf(sqrtf(ssy), EPSF);
    const float sx = invx * QSCALE;
    const float sy = invy * QSCALE;

    unsigned* xw = xq + (size_t)row * 256;
    unsigned* yw = yq + (size_t)row * 256;
    #pragma unroll
    for (int j = 0; j < 4; ++j) {
        int px = __builtin_amdgcn_cvt_pk_fp8_f32(xv[j].x * sx, xv[j].y * sx, 0, false);
        px     = __builtin_amdgcn_cvt_pk_fp8_f32(xv[j].z * sx, xv[j].w * sx, px, true);
        int py = __builtin_amdgcn_cvt_pk_fp8_f32(yv[j].x * sy, yv[j].y * sy, 0, false);
        py     = __builtin_amdgcn_cvt_pk_fp8_f32(yv[j].z * sy, yv[j].w * sy, py, true);
        xw[j * 64 + lane] = (unsigned)px;
        yw[j * 64 + lane] = (unsigned)py;
    }
    if (lane == 0) sdiag[row] = sxy * invx * invy;
}

// load one A/B fragment for mfma_scale_f32_16x16x128_f8f6f4:
// row base + 32 B of k (two 16 B groups 2q, 2q+1, XOR-swizzled by row&7).
__device__ __forceinline__ i32x8_t ld_frag(const unsigned char* base, int q, int h) {
    const i32x4_t lo = *reinterpret_cast<const i32x4_t*>(base + (((2*q)     ^ h) << 4));
    const i32x4_t hi = *reinterpret_cast<const i32x4_t*>(base + (((2*q + 1) ^ h) << 4));
    i32x8_t r;
    r[0] = lo[0]; r[1] = lo[1]; r[2] = lo[2]; r[3] = lo[3];
    r[4] = hi[0]; r[5] = hi[1]; r[6] = hi[2]; r[7] = hi[3];
    return r;
}

// ---------------------------------------------------------------------------
// Kernel 2: S' = 256 * xn*yn^T via MX-fp8 (unit scales), 128x128 tiles,
// BK=128 -> 8 K-iterations, 16 mfma_scale_f32_16x16x128 per wave per iter.
// LDS: 128 B rows, 8 x 16B groups, slot = g ^ (row&7).
// NOTE: __launch_bounds__(256) ONLY — round 3's (256,4) capped VGPRs at 64
// and spilled the accumulators to scratch every K-iter (374 MB WRITE_SIZE,
// 7x regression). The MX live set needs ~150 VGPRs; let the allocator have
// them and take 3 blocks/CU.
// Epilogue: E = exp2(S'/(256*TAU*ln2)), shuffle-reduced row/col partials,
// one atomicAdd per row/col per wave; last block (ticket) computes the loss.
// ---------------------------------------------------------------------------
__global__ __launch_bounds__(256) void gemm_exp_sums(
    const unsigned char* __restrict__ xq, const unsigned char* __restrict__ yq,
    float* __restrict__ rowsum, float* __restrict__ colsum,
    const float* __restrict__ sdiag, float* __restrict__ out,
    unsigned* __restrict__ ticket)
{
    __shared__ __align__(16) unsigned char At[128 * 128];  // 16 KB
    __shared__ __align__(16) unsigned char Bt[128 * 128];  // 16 KB

    const int t    = threadIdx.x;
    const int lane = t & 63;
    const int wave = t >> 6;
    const int q    = lane >> 4;    // quad within wave
    const int l15  = lane & 15;
    const int h    = l15 & 7;      // row&7 for this lane's fragment rows

    const int R0 = blockIdx.y * 128;
    const int C0 = blockIdx.x * 128;
    const int wRow = (wave >> 1) * 64;   // wave's 64x64 quadrant
    const int wCol = (wave & 1) * 64;

    f32x4_t acc[4][4];
    #pragma unroll
    for (int i = 0; i < 4; i++)
        #pragma unroll
        for (int j = 0; j < 4; j++)
            acc[i][j] = (f32x4_t){0.f, 0.f, 0.f, 0.f};

    const int r8  = lane >> 3;           // row within 8-row staging chunk
    const int gsw = (lane & 7) ^ r8;     // swizzled source 16B-group

    for (int kb = 0; kb < DK; kb += 128) {
        __syncthreads();
        #pragma unroll
        for (int c = 0; c < 4; ++c) {
            const int rl = wave * 32 + c * 8 + r8;          // local row 0..127
            async16(xq + (size_t)(R0 + rl) * DK + kb + gsw * 16,
                    &At[(wave * 32 + c * 8) * 128]);
            async16(yq + (size_t)(C0 + rl) * DK + kb + gsw * 16,
                    &Bt[(wave * 32 + c * 8) * 128]);
        }
        __syncthreads();

        i32x8_t bfr[4];
        #pragma unroll
        for (int nt = 0; nt < 4; ++nt)
            bfr[nt] = ld_frag(&Bt[(wCol + nt * 16 + l15) * 128], q, h);

        #pragma unroll
        for (int mt = 0; mt < 4; ++mt) {
            const i32x8_t af = ld_frag(&At[(wRow + mt * 16 + l15) * 128], q, h);
            #pragma unroll
            for (int nt = 0; nt < 4; ++nt)
                acc[mt][nt] = __builtin_amdgcn_mfma_scale_f32_16x16x128_f8f6f4(
                    af, bfr[nt], acc[mt][nt],
                    0, 0,                       // cbsz=fp8(e4m3), blgp=fp8(e4m3)
                    0, 0x7F7F7F7F,              // A scales: E8M0 127 = 2^0
                    0, 0x7F7F7F7F);             // B scales: 2^0
        }
    }

    // Epilogue: E = exp(S/TAU); acc holds 256*S -> exp2(acc / (256*TAU*ln2)).
    const float kScale = (float)(1.0 / (256.0 * 0.07 * 0.6931471805599453));
    float csum[4] = {0.f, 0.f, 0.f, 0.f};
    #pragma unroll
    for (int mt = 0; mt < 4; ++mt) {
        float rsum[4] = {0.f, 0.f, 0.f, 0.f};
        #pragma unroll
        for (int nt = 0; nt < 4; ++nt) {
            #pragma unroll
            for (int r = 0; r < 4; ++r) {
                const float e = exp2f(acc[mt][nt][r] * kScale);
                rsum[r]  += e;
                csum[nt] += e;
            }
        }
        #pragma unroll
        for (int r = 0; r < 4; ++r) {
            float v = rsum[r];
            v += __shfl_xor(v, 1, 64);
            v += __shfl_xor(v, 2, 64);
            v += __shfl_xor(v, 4, 64);
            v += __shfl_xor(v, 8, 64);
            if (l15 == 0)
                atomicAdd(&rowsum[R0 + wRow + mt * 16 + q * 4 + r], v);
        }
    }
    #pragma unroll
    for (int nt = 0; nt < 4; ++nt) {
        float v = csum[nt];
        v += __shfl_xor(v, 16, 64);
        v += __shfl_xor(v, 32, 64);
        if (lane < 16)
            atomicAdd(&colsum[C0 + wCol + nt * 16 + l15], v);
    }

    // ---- fused finalize: last block to finish computes the loss ----------
    __threadfence();                       // release our atomics (agent scope)
    __shared__ unsigned rank;
    if (t == 0) rank = atomicAdd(ticket, 1u);
    __syncthreads();
    if (rank == (unsigned)(gridDim.x * gridDim.y - 1)) {
        __threadfence();                   // acquire: see all blocks' sums
        const float extra = (float)(NB * 1e-6 + 1e-6);
        double local = 0.0;
        for (int i = t; i < NB; i += 256) {
            local += (double)sdiag[i] * (2.0 / 0.07)
                   - (double)logf(rowsum[i] + extra)
                   - (double)logf(colsum[i] + extra);
        }
        #pragma unroll
        for (int off = 1; off < 64; off <<= 1)
            local += __shfl_xor(local, off, 64);
        __shared__ double dred[4];
        if ((t & 63) == 0) dred[t >> 6] = local;
        __syncthreads();
        if (t == 0) {
            const double tot = dred[0] + dred[1] + dred[2] + dred[3];
            out[0] = (float)(tot * (-1.0 / (2.0 * NB)));
        }
    }
}

// ---------------------------------------------------------------------------
extern "C" void kernel_launch(void* const* d_in, const int* in_sizes, int n_in,
                              void* d_out, int out_size, void* d_ws, size_t ws_size,
                              hipStream_t stream)
{
    const float* x = (const float*)d_in[0];
    const float* y = (const float*)d_in[1];
    float* out = (float*)d_out;

    char* ws = (char*)d_ws;
    unsigned char* xq = (unsigned char*)ws;                                 // 4 MB
    unsigned char* yq = (unsigned char*)(ws + (size_t)4 * 1024 * 1024);     // 4 MB
    float* rowsum = (float*)(ws + (size_t)8 * 1024 * 1024);                 // 16 KB
    float* colsum = rowsum + NB;                                            // 16 KB
    float* sdiag  = colsum + NB;                                            // 16 KB
    unsigned* ticket = (unsigned*)(sdiag + NB);                             // 4 B

    normalize_rows<<<NB / 4, 256, 0, stream>>>(x, y, (unsigned*)xq, (unsigned*)yq,
                                               sdiag, rowsum, ticket);

    dim3 grid(NB / 128, NB / 128);
    gemm_exp_sums<<<grid, 256, 0, stream>>>(xq, yq, rowsum, colsum, sdiag, out, ticket);
}

// Round 5
// 167.978 us; speedup vs baseline: 2.8906x; 1.1033x over previous
//
#include <hip/hip_runtime.h>
#include <hip/hip_bf16.h>

#define NB 4096
#define DK 1024           // elements per row (fp8 row = 1024 B)
#define EPSF 1e-6f
#define QSCALE 16.0f      // fp8 pre-scale (power of 2; cancelled exactly in exp)

typedef __attribute__((ext_vector_type(8))) int   i32x8_t;
typedef __attribute__((ext_vector_type(4))) int   i32x4_t;
typedef __attribute__((ext_vector_type(4))) float f32x4_t;

// async global->LDS, 16 B per lane. LDS dest is wave-uniform base + lane*16.
__device__ __forceinline__ void async16(const void* g, void* lds) {
    __builtin_amdgcn_global_load_lds(
        (const __attribute__((address_space(1))) void*)g,
        (__attribute__((address_space(3))) void*)lds, 16, 0, 0);
}

// ---------------------------------------------------------------------------
// Kernel 1: wave-per-row normalize of x and y -> fp8 e4m3 (x QSCALE), plus
// exact fp32 diagonal cos-sim. Also zeroes rowsum/colsum and the ticket.
// ---------------------------------------------------------------------------
__global__ __launch_bounds__(256) void normalize_rows(
    const float* __restrict__ x, const float* __restrict__ y,
    unsigned* __restrict__ xq, unsigned* __restrict__ yq,   // fp8 rows: 256 uints
    float* __restrict__ sdiag, float* __restrict__ zerobuf,
    unsigned* __restrict__ ticket)
{
    const int t = threadIdx.x;
    const int gid = blockIdx.x * 256 + t;
    if (gid < 2 * NB) zerobuf[gid] = 0.f;   // rowsum+colsum contiguous
    if (gid == 0) *ticket = 0u;

    const int wave = t >> 6;
    const int lane = t & 63;
    const int row  = blockIdx.x * 4 + wave;

    const float4* xr = reinterpret_cast<const float4*>(x + (size_t)row * DK);
    const float4* yr = reinterpret_cast<const float4*>(y + (size_t)row * DK);

    float4 xv[4], yv[4];
    float ssx = 0.f, ssy = 0.f, sxy = 0.f;
    #pragma unroll
    for (int j = 0; j < 4; ++j) {
        xv[j] = xr[j * 64 + lane];
        yv[j] = yr[j * 64 + lane];
        ssx += xv[j].x*xv[j].x + xv[j].y*xv[j].y + xv[j].z*xv[j].z + xv[j].w*xv[j].w;
        ssy += yv[j].x*yv[j].x + yv[j].y*yv[j].y + yv[j].z*yv[j].z + yv[j].w*yv[j].w;
        sxy += xv[j].x*yv[j].x + xv[j].y*yv[j].y + xv[j].z*yv[j].z + xv[j].w*yv[j].w;
    }
    #pragma unroll
    for (int off = 1; off < 64; off <<= 1) {
        ssx += __shfl_xor(ssx, off, 64);
        ssy += __shfl_xor(ssy, off, 64);
        sxy += __shfl_xor(sxy, off, 64);
    }
    const float invx = 1.0f / fmaxf(sqrtf(ssx), EPSF);
    const float invy = 1.0f / fmaxf(sqrtf(ssy), EPSF);
    const float sx = invx * QSCALE;
    const float sy = invy * QSCALE;

    unsigned* xw = xq + (size_t)row * 256;
    unsigned* yw = yq + (size_t)row * 256;
    #pragma unroll
    for (int j = 0; j < 4; ++j) {
        int px = __builtin_amdgcn_cvt_pk_fp8_f32(xv[j].x * sx, xv[j].y * sx, 0, false);
        px     = __builtin_amdgcn_cvt_pk_fp8_f32(xv[j].z * sx, xv[j].w * sx, px, true);
        int py = __builtin_amdgcn_cvt_pk_fp8_f32(yv[j].x * sy, yv[j].y * sy, 0, false);
        py     = __builtin_amdgcn_cvt_pk_fp8_f32(yv[j].z * sy, yv[j].w * sy, py, true);
        xw[j * 64 + lane] = (unsigned)px;
        yw[j * 64 + lane] = (unsigned)py;
    }
    if (lane == 0) sdiag[row] = sxy * invx * invy;
}

// ---------------------------------------------------------------------------
// Kernel 2: S' = 256 * xn*yn^T via MX-fp8 (unit scales), 128x128 tiles,
// BK=128, 8 K-iters, 16 mfma_scale_f32_16x16x128 per wave per iter.
// Register economy is the point of this revision (round 4: arch VGPR 232 +
// 64 AGPR acc > 256 unified -> 1 wave/SIMD -> 15x stall):
//   - #pragma unroll 1 on the K-loop (r4's full unroll hoisted 8 iters of
//     addresses into registers)
//   - running 64-bit DMA base pointers (+128/iter), c*8192 added inline
//   - fragment reads: 4 LDS address regs (A/B x lo/hi swizzled slot), rows
//     addressed with compile-time mt*2048 immediates
//   - only bfr[4] held across the mt loop; af loaded per-mt
// Target: ~64 AGPR + <100 arch VGPR -> 3 waves/SIMD, 3 blocks/CU.
// ---------------------------------------------------------------------------
__global__ __launch_bounds__(256) void gemm_exp_sums(
    const unsigned char* __restrict__ xq, const unsigned char* __restrict__ yq,
    float* __restrict__ rowsum, float* __restrict__ colsum,
    const float* __restrict__ sdiag, float* __restrict__ out,
    unsigned* __restrict__ ticket)
{
    __shared__ __align__(16) unsigned char At[128 * 128];  // 16 KB
    __shared__ __align__(16) unsigned char Bt[128 * 128];  // 16 KB

    const int t    = threadIdx.x;
    const int lane = t & 63;
    const int wave = t >> 6;
    const int q    = lane >> 4;    // quad: selects 32B k-chunk (groups 2q,2q+1)
    const int l15  = lane & 15;
    const int h    = l15 & 7;      // row&7 for this lane's fragment rows

    const int R0 = blockIdx.y * 128;
    const int C0 = blockIdx.x * 128;
    const int wRow = (wave >> 1) * 64;   // wave's 64x64 quadrant
    const int wCol = (wave & 1) * 64;

    f32x4_t acc[4][4];
    #pragma unroll
    for (int i = 0; i < 4; i++)
        #pragma unroll
        for (int j = 0; j < 4; j++)
            acc[i][j] = (f32x4_t){0.f, 0.f, 0.f, 0.f};

    // DMA source: lane-invariant running bases + per-lane row/swizzle offset.
    const int r8  = lane >> 3;           // row within 8-row staging chunk
    const int gsw = (lane & 7) ^ r8;     // swizzled source 16B-group
    const unsigned char* pA = xq + (size_t)(R0 + wave * 32 + r8) * DK + gsw * 16;
    const unsigned char* pB = yq + (size_t)(C0 + wave * 32 + r8) * DK + gsw * 16;

    // Fragment read bases: row (wRow|wCol)+l15, slot (2q)^h and (2q+1)^h.
    // mt/nt add 16 rows = 2048 B as compile-time ds_read offsets.
    const unsigned char* baseALo = &At[(wRow + l15) * 128 + (((2*q)    ) ^ h) * 16];
    const unsigned char* baseAHi = &At[(wRow + l15) * 128 + (((2*q) + 1) ^ h) * 16];
    const unsigned char* baseBLo = &Bt[(wCol + l15) * 128 + (((2*q)    ) ^ h) * 16];
    const unsigned char* baseBHi = &Bt[(wCol + l15) * 128 + (((2*q) + 1) ^ h) * 16];

    #pragma unroll 1
    for (int kb = 0; kb < DK; kb += 128) {
        __syncthreads();
        #pragma unroll
        for (int c = 0; c < 4; ++c) {
            async16(pA + c * 8192, &At[(wave * 32 + c * 8) * 128]);
            async16(pB + c * 8192, &Bt[(wave * 32 + c * 8) * 128]);
        }
        pA += 128;
        pB += 128;
        __syncthreads();

        i32x8_t bfr[4];
        #pragma unroll
        for (int nt = 0; nt < 4; ++nt) {
            const i32x4_t lo = *reinterpret_cast<const i32x4_t*>(baseBLo + nt * 2048);
            const i32x4_t hi = *reinterpret_cast<const i32x4_t*>(baseBHi + nt * 2048);
            bfr[nt][0] = lo[0]; bfr[nt][1] = lo[1]; bfr[nt][2] = lo[2]; bfr[nt][3] = lo[3];
            bfr[nt][4] = hi[0]; bfr[nt][5] = hi[1]; bfr[nt][6] = hi[2]; bfr[nt][7] = hi[3];
        }
        #pragma unroll
        for (int mt = 0; mt < 4; ++mt) {
            const i32x4_t lo = *reinterpret_cast<const i32x4_t*>(baseALo + mt * 2048);
            const i32x4_t hi = *reinterpret_cast<const i32x4_t*>(baseAHi + mt * 2048);
            i32x8_t af;
            af[0] = lo[0]; af[1] = lo[1]; af[2] = lo[2]; af[3] = lo[3];
            af[4] = hi[0]; af[5] = hi[1]; af[6] = hi[2]; af[7] = hi[3];
            #pragma unroll
            for (int nt = 0; nt < 4; ++nt)
                acc[mt][nt] = __builtin_amdgcn_mfma_scale_f32_16x16x128_f8f6f4(
                    af, bfr[nt], acc[mt][nt],
                    0, 0,                       // cbsz=fp8(e4m3), blgp=fp8(e4m3)
                    0, 0x7F7F7F7F,              // A scales: E8M0 127 = 2^0
                    0, 0x7F7F7F7F);             // B scales: 2^0
        }
    }

    // Epilogue: E = exp(S/TAU); acc holds 256*S -> exp2(acc / (256*TAU*ln2)).
    const float kScale = (float)(1.0 / (256.0 * 0.07 * 0.6931471805599453));
    float csum[4] = {0.f, 0.f, 0.f, 0.f};
    #pragma unroll
    for (int mt = 0; mt < 4; ++mt) {
        float rsum[4] = {0.f, 0.f, 0.f, 0.f};
        #pragma unroll
        for (int nt = 0; nt < 4; ++nt) {
            #pragma unroll
            for (int r = 0; r < 4; ++r) {
                const float e = exp2f(acc[mt][nt][r] * kScale);
                rsum[r]  += e;
                csum[nt] += e;
            }
        }
        #pragma unroll
        for (int r = 0; r < 4; ++r) {
            float v = rsum[r];
            v += __shfl_xor(v, 1, 64);
            v += __shfl_xor(v, 2, 64);
            v += __shfl_xor(v, 4, 64);
            v += __shfl_xor(v, 8, 64);
            if (l15 == 0)
                atomicAdd(&rowsum[R0 + wRow + mt * 16 + q * 4 + r], v);
        }
    }
    #pragma unroll
    for (int nt = 0; nt < 4; ++nt) {
        float v = csum[nt];
        v += __shfl_xor(v, 16, 64);
        v += __shfl_xor(v, 32, 64);
        if (lane < 16)
            atomicAdd(&colsum[C0 + wCol + nt * 16 + l15], v);
    }

    // ---- fused finalize: last block to finish computes the loss ----------
    __threadfence();                       // release our atomics
    __shared__ unsigned rank;
    if (t == 0) rank = atomicAdd(ticket, 1u);
    __syncthreads();
    if (rank == (unsigned)(gridDim.x * gridDim.y - 1)) {
        __threadfence();                   // acquire: see all blocks' sums
        const float extra = (float)(NB * 1e-6 + 1e-6);
        double local = 0.0;
        for (int i = t; i < NB; i += 256) {
            local += (double)sdiag[i] * (2.0 / 0.07)
                   - (double)logf(rowsum[i] + extra)
                   - (double)logf(colsum[i] + extra);
        }
        #pragma unroll
        for (int off = 1; off < 64; off <<= 1)
            local += __shfl_xor(local, off, 64);
        __shared__ double dred[4];
        if ((t & 63) == 0) dred[t >> 6] = local;
        __syncthreads();
        if (t == 0) {
            const double tot = dred[0] + dred[1] + dred[2] + dred[3];
            out[0] = (float)(tot * (-1.0 / (2.0 * NB)));
        }
    }
}

// ---------------------------------------------------------------------------
extern "C" void kernel_launch(void* const* d_in, const int* in_sizes, int n_in,
                              void* d_out, int out_size, void* d_ws, size_t ws_size,
                              hipStream_t stream)
{
    const float* x = (const float*)d_in[0];
    const float* y = (const float*)d_in[1];
    float* out = (float*)d_out;

    char* ws = (char*)d_ws;
    unsigned char* xq = (unsigned char*)ws;                                 // 4 MB
    unsigned char* yq = (unsigned char*)(ws + (size_t)4 * 1024 * 1024);     // 4 MB
    float* rowsum = (float*)(ws + (size_t)8 * 1024 * 1024);                 // 16 KB
    float* colsum = rowsum + NB;                                            // 16 KB
    float* sdiag  = colsum + NB;                                            // 16 KB
    unsigned* ticket = (unsigned*)(sdiag + NB);                             // 4 B

    normalize_rows<<<NB / 4, 256, 0, stream>>>(x, y, (unsigned*)xq, (unsigned*)yq,
                                               sdiag, rowsum, ticket);

    dim3 grid(NB / 128, NB / 128);
    gemm_exp_sums<<<grid, 256, 0, stream>>>(xq, yq, rowsum, colsum, sdiag, out, ticket);
}

// Round 6
// 113.008 us; speedup vs baseline: 4.2967x; 1.4864x over previous
//
#include <hip/hip_runtime.h>
#include <hip/hip_bf16.h>

#define NB 4096
#define DK 1024           // elements per row (fp8 row = 1024 B)
#define EPSF 1e-6f
#define QSCALE 16.0f      // fp8 pre-scale (power of 2; cancelled exactly in exp)

typedef __attribute__((ext_vector_type(8))) int   i32x8_t;
typedef __attribute__((ext_vector_type(4))) int   i32x4_t;
typedef __attribute__((ext_vector_type(4))) float f32x4_t;

// async global->LDS, 16 B per lane. LDS dest is wave-uniform base + lane*16.
__device__ __forceinline__ void async16(const void* g, void* lds) {
    __builtin_amdgcn_global_load_lds(
        (const __attribute__((address_space(1))) void*)g,
        (__attribute__((address_space(3))) void*)lds, 16, 0, 0);
}

// ---------------------------------------------------------------------------
// Kernel 1: wave-per-row normalize of x and y -> fp8 e4m3 (x QSCALE), plus
// exact fp32 diagonal cos-sim. Also zeroes rowsum/colsum.
// ---------------------------------------------------------------------------
__global__ __launch_bounds__(256) void normalize_rows(
    const float* __restrict__ x, const float* __restrict__ y,
    unsigned* __restrict__ xq, unsigned* __restrict__ yq,   // fp8 rows: 256 uints
    float* __restrict__ sdiag, float* __restrict__ zerobuf)
{
    const int t = threadIdx.x;
    const int gid = blockIdx.x * 256 + t;
    if (gid < 2 * NB) zerobuf[gid] = 0.f;   // rowsum+colsum contiguous

    const int wave = t >> 6;
    const int lane = t & 63;
    const int row  = blockIdx.x * 4 + wave;

    const float4* xr = reinterpret_cast<const float4*>(x + (size_t)row * DK);
    const float4* yr = reinterpret_cast<const float4*>(y + (size_t)row * DK);

    float4 xv[4], yv[4];
    float ssx = 0.f, ssy = 0.f, sxy = 0.f;
    #pragma unroll
    for (int j = 0; j < 4; ++j) {
        xv[j] = xr[j * 64 + lane];
        yv[j] = yr[j * 64 + lane];
        ssx += xv[j].x*xv[j].x + xv[j].y*xv[j].y + xv[j].z*xv[j].z + xv[j].w*xv[j].w;
        ssy += yv[j].x*yv[j].x + yv[j].y*yv[j].y + yv[j].z*yv[j].z + yv[j].w*yv[j].w;
        sxy += xv[j].x*yv[j].x + xv[j].y*yv[j].y + xv[j].z*yv[j].z + xv[j].w*yv[j].w;
    }
    #pragma unroll
    for (int off = 1; off < 64; off <<= 1) {
        ssx += __shfl_xor(ssx, off, 64);
        ssy += __shfl_xor(ssy, off, 64);
        sxy += __shfl_xor(sxy, off, 64);
    }
    const float invx = 1.0f / fmaxf(sqrtf(ssx), EPSF);
    const float invy = 1.0f / fmaxf(sqrtf(ssy), EPSF);
    const float sx = invx * QSCALE;
    const float sy = invy * QSCALE;

    unsigned* xw = xq + (size_t)row * 256;
    unsigned* yw = yq + (size_t)row * 256;
    #pragma unroll
    for (int j = 0; j < 4; ++j) {
        int px = __builtin_amdgcn_cvt_pk_fp8_f32(xv[j].x * sx, xv[j].y * sx, 0, false);
        px     = __builtin_amdgcn_cvt_pk_fp8_f32(xv[j].z * sx, xv[j].w * sx, px, true);
        int py = __builtin_amdgcn_cvt_pk_fp8_f32(yv[j].x * sy, yv[j].y * sy, 0, false);
        py     = __builtin_amdgcn_cvt_pk_fp8_f32(yv[j].z * sy, yv[j].w * sy, py, true);
        xw[j * 64 + lane] = (unsigned)px;
        yw[j * 64 + lane] = (unsigned)py;
    }
    if (lane == 0) sdiag[row] = sxy * invx * invy;
}

// ---------------------------------------------------------------------------
// Kernel 2: S' = 256 * xn*yn^T via MX-fp8 (unit scales), 128x128 tiles,
// BK=128, 8 K-iters, 16 mfma_scale_f32_16x16x128 per wave per iter.
// Register-lean body (r5: VGPR 76, no spills). NO fused finalize: r3-r5's
// per-block __threadfence() (agent-scope release -> buffer_wbl2 L2 writeback
// on multi-XCD gfx950) serialized 1024 blocks at the TCC and left every pipe
// idle (MfmaUtil 6.6% while MFMA busy-time matched the 7.4us floor).
// Finalize is a separate kernel; stream ordering provides visibility.
// ---------------------------------------------------------------------------
__global__ __launch_bounds__(256) void gemm_exp_sums(
    const unsigned char* __restrict__ xq, const unsigned char* __restrict__ yq,
    float* __restrict__ rowsum, float* __restrict__ colsum)
{
    __shared__ __align__(16) unsigned char At[128 * 128];  // 16 KB
    __shared__ __align__(16) unsigned char Bt[128 * 128];  // 16 KB

    const int t    = threadIdx.x;
    const int lane = t & 63;
    const int wave = t >> 6;
    const int q    = lane >> 4;    // quad: selects 32B k-chunk (groups 2q,2q+1)
    const int l15  = lane & 15;
    const int h    = l15 & 7;      // row&7 for this lane's fragment rows

    const int R0 = blockIdx.y * 128;
    const int C0 = blockIdx.x * 128;
    const int wRow = (wave >> 1) * 64;   // wave's 64x64 quadrant
    const int wCol = (wave & 1) * 64;

    f32x4_t acc[4][4];
    #pragma unroll
    for (int i = 0; i < 4; i++)
        #pragma unroll
        for (int j = 0; j < 4; j++)
            acc[i][j] = (f32x4_t){0.f, 0.f, 0.f, 0.f};

    // DMA source: lane-invariant running bases + per-lane row/swizzle offset.
    const int r8  = lane >> 3;           // row within 8-row staging chunk
    const int gsw = (lane & 7) ^ r8;     // swizzled source 16B-group
    const unsigned char* pA = xq + (size_t)(R0 + wave * 32 + r8) * DK + gsw * 16;
    const unsigned char* pB = yq + (size_t)(C0 + wave * 32 + r8) * DK + gsw * 16;

    // Fragment read bases: row (wRow|wCol)+l15, slot (2q)^h and (2q+1)^h.
    // mt/nt add 16 rows = 2048 B as compile-time ds_read offsets.
    const unsigned char* baseALo = &At[(wRow + l15) * 128 + (((2*q)    ) ^ h) * 16];
    const unsigned char* baseAHi = &At[(wRow + l15) * 128 + (((2*q) + 1) ^ h) * 16];
    const unsigned char* baseBLo = &Bt[(wCol + l15) * 128 + (((2*q)    ) ^ h) * 16];
    const unsigned char* baseBHi = &Bt[(wCol + l15) * 128 + (((2*q) + 1) ^ h) * 16];

    #pragma unroll 1
    for (int kb = 0; kb < DK; kb += 128) {
        __syncthreads();
        #pragma unroll
        for (int c = 0; c < 4; ++c) {
            async16(pA + c * 8192, &At[(wave * 32 + c * 8) * 128]);
            async16(pB + c * 8192, &Bt[(wave * 32 + c * 8) * 128]);
        }
        pA += 128;
        pB += 128;
        __syncthreads();

        i32x8_t bfr[4];
        #pragma unroll
        for (int nt = 0; nt < 4; ++nt) {
            const i32x4_t lo = *reinterpret_cast<const i32x4_t*>(baseBLo + nt * 2048);
            const i32x4_t hi = *reinterpret_cast<const i32x4_t*>(baseBHi + nt * 2048);
            bfr[nt][0] = lo[0]; bfr[nt][1] = lo[1]; bfr[nt][2] = lo[2]; bfr[nt][3] = lo[3];
            bfr[nt][4] = hi[0]; bfr[nt][5] = hi[1]; bfr[nt][6] = hi[2]; bfr[nt][7] = hi[3];
        }
        #pragma unroll
        for (int mt = 0; mt < 4; ++mt) {
            const i32x4_t lo = *reinterpret_cast<const i32x4_t*>(baseALo + mt * 2048);
            const i32x4_t hi = *reinterpret_cast<const i32x4_t*>(baseAHi + mt * 2048);
            i32x8_t af;
            af[0] = lo[0]; af[1] = lo[1]; af[2] = lo[2]; af[3] = lo[3];
            af[4] = hi[0]; af[5] = hi[1]; af[6] = hi[2]; af[7] = hi[3];
            #pragma unroll
            for (int nt = 0; nt < 4; ++nt)
                acc[mt][nt] = __builtin_amdgcn_mfma_scale_f32_16x16x128_f8f6f4(
                    af, bfr[nt], acc[mt][nt],
                    0, 0,                       // cbsz=fp8(e4m3), blgp=fp8(e4m3)
                    0, 0x7F7F7F7F,              // A scales: E8M0 127 = 2^0
                    0, 0x7F7F7F7F);             // B scales: 2^0
        }
    }

    // Epilogue: E = exp(S/TAU); acc holds 256*S -> exp2(acc / (256*TAU*ln2)).
    const float kScale = (float)(1.0 / (256.0 * 0.07 * 0.6931471805599453));
    float csum[4] = {0.f, 0.f, 0.f, 0.f};
    #pragma unroll
    for (int mt = 0; mt < 4; ++mt) {
        float rsum[4] = {0.f, 0.f, 0.f, 0.f};
        #pragma unroll
        for (int nt = 0; nt < 4; ++nt) {
            #pragma unroll
            for (int r = 0; r < 4; ++r) {
                const float e = exp2f(acc[mt][nt][r] * kScale);
                rsum[r]  += e;
                csum[nt] += e;
            }
        }
        #pragma unroll
        for (int r = 0; r < 4; ++r) {
            float v = rsum[r];
            v += __shfl_xor(v, 1, 64);
            v += __shfl_xor(v, 2, 64);
            v += __shfl_xor(v, 4, 64);
            v += __shfl_xor(v, 8, 64);
            if (l15 == 0)
                atomicAdd(&rowsum[R0 + wRow + mt * 16 + q * 4 + r], v);
        }
    }
    #pragma unroll
    for (int nt = 0; nt < 4; ++nt) {
        float v = csum[nt];
        v += __shfl_xor(v, 16, 64);
        v += __shfl_xor(v, 32, 64);
        if (lane < 16)
            atomicAdd(&colsum[C0 + wCol + nt * 16 + l15], v);
    }
}

// ---------------------------------------------------------------------------
// Kernel 3: loss = -1/(2B) [ (2/TAU) * sum(sdiag)
//                            - sum(log(rowsum+extra)) - sum(log(colsum+extra)) ]
// Double accumulation (float tree-sum error would be too close to threshold).
// ---------------------------------------------------------------------------
__global__ __launch_bounds__(1024) void finalize(
    const float* __restrict__ rowsum, const float* __restrict__ colsum,
    const float* __restrict__ sdiag, float* __restrict__ out)
{
    const float extra = (float)(NB * 1e-6 + 1e-6);
    double local = 0.0;
    for (int i = threadIdx.x; i < NB; i += 1024) {
        local += (double)sdiag[i] * (2.0 / 0.07)
               - (double)logf(rowsum[i] + extra)
               - (double)logf(colsum[i] + extra);
    }
    #pragma unroll
    for (int off = 1; off < 64; off <<= 1)
        local += __shfl_xor(local, off, 64);
    __shared__ double dred[16];
    const int wave = threadIdx.x >> 6;
    if ((threadIdx.x & 63) == 0) dred[wave] = local;
    __syncthreads();
    if (threadIdx.x == 0) {
        double tot = 0.0;
        #pragma unroll
        for (int w = 0; w < 16; ++w) tot += dred[w];
        out[0] = (float)(tot * (-1.0 / (2.0 * NB)));
    }
}

// ---------------------------------------------------------------------------
extern "C" void kernel_launch(void* const* d_in, const int* in_sizes, int n_in,
                              void* d_out, int out_size, void* d_ws, size_t ws_size,
                              hipStream_t stream)
{
    const float* x = (const float*)d_in[0];
    const float* y = (const float*)d_in[1];
    float* out = (float*)d_out;

    char* ws = (char*)d_ws;
    unsigned char* xq = (unsigned char*)ws;                                 // 4 MB
    unsigned char* yq = (unsigned char*)(ws + (size_t)4 * 1024 * 1024);     // 4 MB
    float* rowsum = (float*)(ws + (size_t)8 * 1024 * 1024);                 // 16 KB
    float* colsum = rowsum + NB;                                            // 16 KB
    float* sdiag  = colsum + NB;                                            // 16 KB

    normalize_rows<<<NB / 4, 256, 0, stream>>>(x, y, (unsigned*)xq, (unsigned*)yq,
                                               sdiag, rowsum);

    dim3 grid(NB / 128, NB / 128);
    gemm_exp_sums<<<grid, 256, 0, stream>>>(xq, yq, rowsum, colsum);

    finalize<<<1, 1024, 0, stream>>>(rowsum, colsum, sdiag, out);
}

// Round 7
// 112.142 us; speedup vs baseline: 4.3299x; 1.0077x over previous
//
#include <hip/hip_runtime.h>
#include <hip/hip_bf16.h>

#define NB 4096
#define DK 1024           // elements per row (fp8 row = 1024 B)
#define EPSF 1e-6f
#define QSCALE 16.0f      // fp8 pre-scale (power of 2; cancelled exactly in exp)

typedef __attribute__((ext_vector_type(8))) int   i32x8_t;
typedef __attribute__((ext_vector_type(4))) int   i32x4_t;
typedef __attribute__((ext_vector_type(4))) float f32x4_t;

// ---------------------------------------------------------------------------
// Fragment-swizzled fp8 layout (both matrices): for row, k:
//   p = row>>4, r = row&15, kb = k>>7, q = (k>>5)&3, b = k&31
//   byte offset = (p*32 + kb*4 + q)*512 + r*32 + b
// A wave's MFMA fragment (lane = q*16 + l15) for panel p, k-block kb is then
// 64 lanes x 32 contiguous bytes starting at (p*32+kb*4+q)*512 + l15*32 —
// i.e. two perfectly coalesced global_load_dwordx4 per fragment. Bytes are
// identical to the r5 LDS fragments (absmax-0 proven).
// ---------------------------------------------------------------------------

// ---------------------------------------------------------------------------
// Kernel 1: wave-per-row normalize of x and y -> fp8 e4m3 (x QSCALE) written
// in fragment-swizzled layout, plus exact fp32 diagonal cos-sim. Also zeroes
// rowsum/colsum.
// ---------------------------------------------------------------------------
__global__ __launch_bounds__(256) void normalize_rows(
    const float* __restrict__ x, const float* __restrict__ y,
    unsigned* __restrict__ xq, unsigned* __restrict__ yq,
    float* __restrict__ sdiag, float* __restrict__ zerobuf)
{
    const int t = threadIdx.x;
    const int gid = blockIdx.x * 256 + t;
    if (gid < 2 * NB) zerobuf[gid] = 0.f;   // rowsum+colsum contiguous

    const int wave = t >> 6;
    const int lane = t & 63;
    const int row  = blockIdx.x * 4 + wave;

    const float4* xr = reinterpret_cast<const float4*>(x + (size_t)row * DK);
    const float4* yr = reinterpret_cast<const float4*>(y + (size_t)row * DK);

    float4 xv[4], yv[4];
    float ssx = 0.f, ssy = 0.f, sxy = 0.f;
    #pragma unroll
    for (int j = 0; j < 4; ++j) {
        xv[j] = xr[j * 64 + lane];
        yv[j] = yr[j * 64 + lane];
        ssx += xv[j].x*xv[j].x + xv[j].y*xv[j].y + xv[j].z*xv[j].z + xv[j].w*xv[j].w;
        ssy += yv[j].x*yv[j].x + yv[j].y*yv[j].y + yv[j].z*yv[j].z + yv[j].w*yv[j].w;
        sxy += xv[j].x*yv[j].x + xv[j].y*yv[j].y + xv[j].z*yv[j].z + xv[j].w*yv[j].w;
    }
    #pragma unroll
    for (int off = 1; off < 64; off <<= 1) {
        ssx += __shfl_xor(ssx, off, 64);
        ssy += __shfl_xor(ssy, off, 64);
        sxy += __shfl_xor(sxy, off, 64);
    }
    const float invx = 1.0f / fmaxf(sqrtf(ssx), EPSF);
    const float invy = 1.0f / fmaxf(sqrtf(ssy), EPSF);
    const float sx = invx * QSCALE;
    const float sy = invy * QSCALE;

    // Swizzled destination for lane's float4 j (k0 = j*256 + lane*4):
    //   kb = j*2 + (lane>>5), q = (lane>>3)&3, b = (lane&7)*4
    const int p = row >> 4, r = row & 15;
    const int qs = (lane >> 3) & 3;
    const int bs = (lane & 7) * 4;
    #pragma unroll
    for (int j = 0; j < 4; ++j) {
        const int kb = j * 2 + (lane >> 5);
        const unsigned off = ((unsigned)(p * 32 + kb * 4 + qs) * 512 + r * 32 + bs) >> 2;
        int px = __builtin_amdgcn_cvt_pk_fp8_f32(xv[j].x * sx, xv[j].y * sx, 0, false);
        px     = __builtin_amdgcn_cvt_pk_fp8_f32(xv[j].z * sx, xv[j].w * sx, px, true);
        int py = __builtin_amdgcn_cvt_pk_fp8_f32(yv[j].x * sy, yv[j].y * sy, 0, false);
        py     = __builtin_amdgcn_cvt_pk_fp8_f32(yv[j].z * sy, yv[j].w * sy, py, true);
        xq[off] = (unsigned)px;
        yq[off] = (unsigned)py;
    }
    if (lane == 0) sdiag[row] = sxy * invx * invy;
}

// ---------------------------------------------------------------------------
// Kernel 2: S' = 256 * xn*yn^T via MX-fp8 (unit scales), 128x128 tiles.
// NO LDS, NO barriers: fragments load directly from the swizzled global
// layout (L2/L3-resident, 4 MB per matrix). K-loop per wave: 16 coalesced
// global_load_dwordx4 + 16 mfma_scale per kb, 8 kb iterations. Waves
// self-overlap; no vmcnt(0)+barrier drain (r6's limiter at 8 K-iters).
// Epilogue: E = exp2(S'/(256*TAU*ln2)), shuffle-reduced row/col partials,
// one atomicAdd per row/col per wave.
// ---------------------------------------------------------------------------
__global__ __launch_bounds__(256) void gemm_exp_sums(
    const unsigned char* __restrict__ xq, const unsigned char* __restrict__ yq,
    float* __restrict__ rowsum, float* __restrict__ colsum)
{
    const int t    = threadIdx.x;
    const int lane = t & 63;
    const int wave = t >> 6;
    const int q    = lane >> 4;    // quad: selects 32B k-chunk
    const int l15  = lane & 15;

    const int R0 = blockIdx.y * 128;
    const int C0 = blockIdx.x * 128;
    const int wRow = (wave >> 1) * 64;   // wave's 64x64 quadrant
    const int wCol = (wave & 1) * 64;

    f32x4_t acc[4][4];
    #pragma unroll
    for (int i = 0; i < 4; i++)
        #pragma unroll
        for (int j = 0; j < 4; j++)
            acc[i][j] = (f32x4_t){0.f, 0.f, 0.f, 0.f};

    // Panel bases: panel index pA = (R0+wRow)/16 + mt, chunk (pA*32+kb*4+q)*512.
    // mt step = 32*512 = 16384 B; kb step = 4*512 = 2048 B.
    const unsigned char* Abase =
        xq + (size_t)(((R0 + wRow) >> 4) * 32 + q) * 512 + l15 * 32;
    const unsigned char* Bbase =
        yq + (size_t)(((C0 + wCol) >> 4) * 32 + q) * 512 + l15 * 32;

    #pragma unroll 1
    for (int kb = 0; kb < 8; ++kb) {
        const unsigned char* Ak = Abase + kb * 2048;
        const unsigned char* Bk = Bbase + kb * 2048;

        i32x8_t bfr[4];
        #pragma unroll
        for (int nt = 0; nt < 4; ++nt) {
            const i32x4_t lo = *reinterpret_cast<const i32x4_t*>(Bk + nt * 16384);
            const i32x4_t hi = *reinterpret_cast<const i32x4_t*>(Bk + nt * 16384 + 16);
            bfr[nt][0] = lo[0]; bfr[nt][1] = lo[1]; bfr[nt][2] = lo[2]; bfr[nt][3] = lo[3];
            bfr[nt][4] = hi[0]; bfr[nt][5] = hi[1]; bfr[nt][6] = hi[2]; bfr[nt][7] = hi[3];
        }
        #pragma unroll
        for (int mt = 0; mt < 4; ++mt) {
            const i32x4_t lo = *reinterpret_cast<const i32x4_t*>(Ak + mt * 16384);
            const i32x4_t hi = *reinterpret_cast<const i32x4_t*>(Ak + mt * 16384 + 16);
            i32x8_t af;
            af[0] = lo[0]; af[1] = lo[1]; af[2] = lo[2]; af[3] = lo[3];
            af[4] = hi[0]; af[5] = hi[1]; af[6] = hi[2]; af[7] = hi[3];
            #pragma unroll
            for (int nt = 0; nt < 4; ++nt)
                acc[mt][nt] = __builtin_amdgcn_mfma_scale_f32_16x16x128_f8f6f4(
                    af, bfr[nt], acc[mt][nt],
                    0, 0,                       // cbsz=fp8(e4m3), blgp=fp8(e4m3)
                    0, 0x7F7F7F7F,              // A scales: E8M0 127 = 2^0
                    0, 0x7F7F7F7F);             // B scales: 2^0
        }
    }

    // Epilogue: E = exp(S/TAU); acc holds 256*S -> exp2(acc / (256*TAU*ln2)).
    const float kScale = (float)(1.0 / (256.0 * 0.07 * 0.6931471805599453));
    float csum[4] = {0.f, 0.f, 0.f, 0.f};
    #pragma unroll
    for (int mt = 0; mt < 4; ++mt) {
        float rsum[4] = {0.f, 0.f, 0.f, 0.f};
        #pragma unroll
        for (int nt = 0; nt < 4; ++nt) {
            #pragma unroll
            for (int r = 0; r < 4; ++r) {
                const float e = exp2f(acc[mt][nt][r] * kScale);
                rsum[r]  += e;
                csum[nt] += e;
            }
        }
        #pragma unroll
        for (int r = 0; r < 4; ++r) {
            float v = rsum[r];
            v += __shfl_xor(v, 1, 64);
            v += __shfl_xor(v, 2, 64);
            v += __shfl_xor(v, 4, 64);
            v += __shfl_xor(v, 8, 64);
            if (l15 == 0)
                atomicAdd(&rowsum[R0 + wRow + mt * 16 + q * 4 + r], v);
        }
    }
    #pragma unroll
    for (int nt = 0; nt < 4; ++nt) {
        float v = csum[nt];
        v += __shfl_xor(v, 16, 64);
        v += __shfl_xor(v, 32, 64);
        if (lane < 16)
            atomicAdd(&colsum[C0 + wCol + nt * 16 + l15], v);
    }
}

// ---------------------------------------------------------------------------
// Kernel 3: loss = -1/(2B) [ (2/TAU) * sum(sdiag)
//                            - sum(log(rowsum+extra)) - sum(log(colsum+extra)) ]
// Double accumulation (float tree-sum error would be too close to threshold).
// ---------------------------------------------------------------------------
__global__ __launch_bounds__(1024) void finalize(
    const float* __restrict__ rowsum, const float* __restrict__ colsum,
    const float* __restrict__ sdiag, float* __restrict__ out)
{
    const float extra = (float)(NB * 1e-6 + 1e-6);
    double local = 0.0;
    for (int i = threadIdx.x; i < NB; i += 1024) {
        local += (double)sdiag[i] * (2.0 / 0.07)
               - (double)logf(rowsum[i] + extra)
               - (double)logf(colsum[i] + extra);
    }
    #pragma unroll
    for (int off = 1; off < 64; off <<= 1)
        local += __shfl_xor(local, off, 64);
    __shared__ double dred[16];
    const int wave = threadIdx.x >> 6;
    if ((threadIdx.x & 63) == 0) dred[wave] = local;
    __syncthreads();
    if (threadIdx.x == 0) {
        double tot = 0.0;
        #pragma unroll
        for (int w = 0; w < 16; ++w) tot += dred[w];
        out[0] = (float)(tot * (-1.0 / (2.0 * NB)));
    }
}

// ---------------------------------------------------------------------------
extern "C" void kernel_launch(void* const* d_in, const int* in_sizes, int n_in,
                              void* d_out, int out_size, void* d_ws, size_t ws_size,
                              hipStream_t stream)
{
    const float* x = (const float*)d_in[0];
    const float* y = (const float*)d_in[1];
    float* out = (float*)d_out;

    char* ws = (char*)d_ws;
    unsigned char* xq = (unsigned char*)ws;                                 // 4 MB swizzled
    unsigned char* yq = (unsigned char*)(ws + (size_t)4 * 1024 * 1024);     // 4 MB swizzled
    float* rowsum = (float*)(ws + (size_t)8 * 1024 * 1024);                 // 16 KB
    float* colsum = rowsum + NB;                                            // 16 KB
    float* sdiag  = colsum + NB;                                            // 16 KB

    normalize_rows<<<NB / 4, 256, 0, stream>>>(x, y, (unsigned*)xq, (unsigned*)yq,
                                               sdiag, rowsum);

    dim3 grid(NB / 128, NB / 128);
    gemm_exp_sums<<<grid, 256, 0, stream>>>(xq, yq, rowsum, colsum);

    finalize<<<1, 1024, 0, stream>>>(rowsum, colsum, sdiag, out);
}